// Round 10
// baseline (495.068 us; speedup 1.0000x reference)
//
#include <hip/hip_runtime.h>
#include <hip/hip_bf16.h>

// Problem constants
#define B_   2
#define N_   50000
#define FD_  13
#define E_   250000
#define M_   128
#define H_   128

typedef __attribute__((ext_vector_type(8))) short  short8;
typedef __attribute__((ext_vector_type(8))) __bf16 bf16x8;
typedef __attribute__((ext_vector_type(4))) float  f32x4;
typedef __attribute__((ext_vector_type(4))) unsigned int uint4v;
typedef __attribute__((ext_vector_type(8))) unsigned short ushort8;

// ws layout: [agg f32 4*N*128][hist][sorted(packed st)][frags]  (~107 MB)
#define AGG_BYTES  (4ull * N_ * 128 * 4)          // 102,400,000
#define HIST_BYTES (4ull * N_ * 4)                // 800,000
#define SORT_BYTES (4ull * E_ * 4)                // 4,000,000
// fragment offsets in ushort units (each frag = 64 lanes * 8 ush = 1KB)
#define OFF_EW1 0u
#define OFF_WW1 8192u
#define OFF_EW2 16384u
#define OFF_XW1 32768u
#define OFF_YW1 40960u
#define OFF_XW2 49152u
#define OFF_NW1 65536u    // 72 frags (K=288 reordered: [agg_h 0..127|agg_w 128..255|z 256..268|pad])
#define OFF_NW2 102400u

__device__ __forceinline__ float bf2f(unsigned short u) {
    unsigned int v = ((unsigned int)u) << 16;
    return __builtin_bit_cast(float, v);
}
// HW bf16 convert on gfx950.
__device__ __forceinline__ unsigned short f2bf(float f) {
    __bf16 h = (__bf16)f;
    return __builtin_bit_cast(unsigned short, h);
}
// exp2-folded transcendentals (saves one VALU op vs __expf(x+x) path).
__device__ __forceinline__ float tanh_fast(float x) {
    float e = __builtin_amdgcn_exp2f(x * 2.8853900817779268f);   // e^(2x)
    float r = __builtin_amdgcn_rcpf(e + 1.0f);
    return __builtin_fmaf(-2.0f, r, 1.0f);         // 1 - 2/(e+1)
}
__device__ __forceinline__ float sigmoid_fast(float x) {
    float e = __builtin_amdgcn_exp2f(x * -1.4426950408889634f);  // e^(-x)
    return __builtin_amdgcn_rcpf(1.0f + e);
}
__device__ __forceinline__ f32x4 mfma16(short8 a, short8 b, f32x4 c) {
    return __builtin_amdgcn_mfma_f32_16x16x32_bf16(
        __builtin_bit_cast(bf16x8, a), __builtin_bit_cast(bf16x8, b), c, 0, 0, 0);
}

// ---------------------------------------------------------------------------
// Prep: fp32 weights -> bf16 B-fragment-major. R10: 256-thread blocks; lanes
// 0..63 do the frag work (unchanged), ALL threads grid-stride-zero hist AND
// agg (102.4 MB). prep's CUs were idle; the fill rides for ~free here and
// comes OFF scatter's critical path. agg is untouched until edge (3 launches
// later) — safe.
// ---------------------------------------------------------------------------
__global__ void prep_kernel(const float* __restrict__ ew1, const float* __restrict__ ww1,
                            const float* __restrict__ ew2, const float* __restrict__ xw1,
                            const float* __restrict__ yw1, const float* __restrict__ xw2,
                            const float* __restrict__ nw1, const float* __restrict__ nw2,
                            unsigned short* __restrict__ fb,
                            uint4v* __restrict__ hist4, uint4v* __restrict__ agg4) {
    const int m = blockIdx.y, f = blockIdx.x, tid = threadIdx.x;
    {
        const unsigned int flat = ((unsigned int)m * gridDim.x + (unsigned int)f) * 256u
                                + (unsigned int)tid;
        const unsigned int nthr = gridDim.x * gridDim.y * 256u;   // 147,456
        const uint4v zv = {0u, 0u, 0u, 0u};
        for (unsigned int i = flat; i < 6400000u; i += nthr) agg4[i] = zv;  // agg 102.4 MB
        for (unsigned int i = flat; i < 50000u;  i += nthr) hist4[i] = zv;  // hist 800 KB
    }
    if (tid >= 64) return;
    const int l = tid;
    const float* src; int K, Nn, KS; unsigned int off;
    switch (m) {
        case 0: src = ew1; K = 34;  Nn = 128; KS = 2; off = OFF_EW1; break;
        case 1: src = ww1; K = 34;  Nn = 128; KS = 2; off = OFF_WW1; break;
        case 2: src = ew2; K = 128; Nn = 128; KS = 4; off = OFF_EW2; break;
        case 3: src = xw1; K = 34;  Nn = 128; KS = 2; off = OFF_XW1; break;
        case 4: src = yw1; K = 34;  Nn = 128; KS = 2; off = OFF_YW1; break;
        case 5: src = xw2; K = 128; Nn = 128; KS = 4; off = OFF_XW2; break;
        case 6: src = nw1; K = 269; Nn = 128; KS = 9; off = OFF_NW1; break;
        default: src = nw2; K = 128; Nn = 13; KS = 4; off = OFF_NW2; break;
    }
    int NT = (Nn + 15) / 16;
    if (f >= KS * NT) return;
    int ks = f / NT, nt = f % NT;
    int n = nt * 16 + (l & 15);
    unsigned short* dst = fb + off + ((unsigned int)f * 64u + (unsigned int)l) * 8u;
    #pragma unroll
    for (int j = 0; j < 8; j++) {
        int k = ks * 32 + ((l >> 4) * 8) + j;
        int kk = k; bool valid = (k < K) && (n < Nn);
        if (m == 6) {
            if (k < 256)      kk = k + 13;
            else if (k < 269) kk = k - 256;
            else              valid = false;
            valid = valid && (n < Nn);
        }
        dst[j] = valid ? f2bf(src[kk * Nn + n]) : (unsigned short)0;
    }
}

// ---------------------------------------------------------------------------
// Counting sort of edges by target, per pass p (p&1=batch, p>>1=set).
// ---------------------------------------------------------------------------
__global__ void hist_kernel(const int* __restrict__ ehh, const int* __restrict__ eww,
                            int* __restrict__ hist) {
    int p = blockIdx.y, idx = blockIdx.x * 256 + threadIdx.x;
    if (idx >= E_) return;
    const int* eg = ((p >> 1) ? eww : ehh) + (size_t)(p & 1) * 2 * E_;
    atomicAdd(&hist[p * N_ + eg[E_ + idx]], 1);
}

// chunk = 52 ints (208 B, 16B-aligned) per thread; values register-cached.
__global__ void scan_kernel(int* __restrict__ hist) {
    __shared__ int part[1024];
    const int p = blockIdx.x, tid = threadIdx.x;
    int* h = hist + p * N_;
    const int lo = tid * 52;
    int cnt = N_ - lo; if (cnt < 0) cnt = 0; if (cnt > 52) cnt = 52;
    int v[52];
    int sum = 0;
    if (cnt == 52) {
        const int4* src = (const int4*)(h + lo);
        #pragma unroll
        for (int i = 0; i < 13; i++) {
            int4 t = src[i];
            v[4*i] = t.x; v[4*i+1] = t.y; v[4*i+2] = t.z; v[4*i+3] = t.w;
        }
        #pragma unroll
        for (int i = 0; i < 52; i++) sum += v[i];
    } else {
        for (int i = 0; i < cnt; i++) sum += h[lo + i];
    }
    part[tid] = sum;
    __syncthreads();
    for (int off = 1; off < 1024; off <<= 1) {
        int t = (tid >= off) ? part[tid - off] : 0;
        __syncthreads();
        part[tid] += t;
        __syncthreads();
    }
    int excl = (tid == 0) ? 0 : part[tid - 1];
    if (cnt == 52) {
        int4* dst = (int4*)(h + lo);
        #pragma unroll
        for (int i = 0; i < 13; i++) {
            int4 o;
            o.x = excl; excl += v[4*i];
            o.y = excl; excl += v[4*i+1];
            o.z = excl; excl += v[4*i+2];
            o.w = excl; excl += v[4*i+3];
            dst[i] = o;
        }
    } else {
        for (int i = 0; i < cnt; i++) { int t = h[lo + i]; h[lo + i] = excl; excl += t; }
    }
}

// Writes PACKED endpoints (s | t<<16; N=50000 < 2^16) at the sorted position.
// R10: zero-fill moved to prep — scatter is back to pure scatter.
__global__ void scatter_kernel(const int* __restrict__ ehh, const int* __restrict__ eww,
                               int* __restrict__ hist, unsigned int* __restrict__ sorted) {
    int p = blockIdx.y, idx = blockIdx.x * 256 + threadIdx.x;
    if (idx >= E_) return;
    const int* eg = ((p >> 1) ? eww : ehh) + (size_t)(p & 1) * 2 * E_;
    int s = eg[idx];
    int t = eg[E_ + idx];
    int pos = atomicAdd(&hist[p * N_ + t], 1);   // after: hist[t] = end offset
    sorted[(size_t)p * E_ + pos] = (unsigned int)s | ((unsigned int)t << 16);
}

// ---------------------------------------------------------------------------
// Edge kernel — EXACT R6 structure (proven 192 us), exp2 transcendentals.
// 3 blocks/CU is FINAL: 4/CU (R7) and 5/CU (R4) blow the L2 dirty-line
// window (+55..+600 MB HBM); 8-wave blocks (R9) double the reduce cost;
// bf16 agg (R8) loses on sub-dword stores. Monolithic Hbuf, 256 threads,
// window-permuted rows + segmented reduce, boundary-only f32 atomics.
// ---------------------------------------------------------------------------
__launch_bounds__(256, 3)
__global__ void edge_kernel_agg(const float* __restrict__ z,
                                const unsigned int* __restrict__ sorted,
                                const unsigned short* __restrict__ fb,
                                float* __restrict__ agg,
                                const float* __restrict__ eb1, const float* __restrict__ wb1,
                                const float* __restrict__ ww2, const float* __restrict__ wb2,
                                const float* __restrict__ eb2,
                                const float* __restrict__ xb1, const float* __restrict__ yb1,
                                const float* __restrict__ yw2, const float* __restrict__ yb2,
                                const float* __restrict__ xb2) {
    __shared__ alignas(16) unsigned short Abuf[128][48];   // cols 0..39 used
    __shared__ alignas(16) unsigned short Hbuf[128][136];
    __shared__ float w_acc[128];   // gate partial sums, then sigmoid in place
    __shared__ int   tgt_s[128];   // target per ROW (-1 = invalid/pad)

    const int tid  = threadIdx.x;
    const int lane = tid & 63, wv = tid >> 6, quad = lane >> 4, c = lane & 15;
    const int pass = blockIdx.y, b = pass & 1, set = pass >> 1;
    const int ebase = blockIdx.x * 128;

    const float* zb = z + (size_t)b * N_ * FD_;
    float* aggp = agg + (size_t)pass * N_ * 128;

    const short8* Fm1 = (const short8*)(fb + (set ? OFF_XW1 : OFF_EW1));
    const short8* Fw1 = (const short8*)(fb + (set ? OFF_YW1 : OFF_WW1));
    const short8* Fm2 = (const short8*)(fb + (set ? OFF_XW2 : OFF_EW2));
    const float* B1m = set ? xb1 : eb1;
    const float* B1w = set ? yb1 : wb1;
    const float* B2m = set ? xb2 : eb2;
    const float* Wv2 = set ? yw2 : ww2;
    const float wbias = (set ? yb2 : wb2)[0];

    const int nt0 = wv * 2;
    short8 bm[2][2], bw[2][2], b2f[2][4];
    float bias1m[2], bias1w[2], bias2m[2], w2v[2];
    #pragma unroll
    for (int i = 0; i < 2; i++) {
        int nt = nt0 + i, n = nt * 16 + c;
        #pragma unroll
        for (int ks = 0; ks < 2; ks++) { bm[i][ks] = Fm1[(ks * 8 + nt) * 64 + lane];
                                         bw[i][ks] = Fw1[(ks * 8 + nt) * 64 + lane]; }
        #pragma unroll
        for (int ks = 0; ks < 4; ks++) { b2f[i][ks] = Fm2[(ks * 8 + nt) * 64 + lane]; }
        bias1m[i] = B1m[n]; bias1w[i] = B1w[n];
        bias2m[i] = B2m[n]; w2v[i] = Wv2[n];
    }

    // ---- Stage edge features (threads 0..127, one sorted edge each) ----
    // Row p holds sorted edge ebase + wpos(p), wpos = quad(p)*32 + rt(p)*4 + r(p)
    if (tid < 128) {
        const int e = tid;                                 // Abuf/Hbuf row
        const int prt = e >> 4, pqd = (e >> 2) & 3, prr = e & 3;
        const int wpos = pqd * 32 + prt * 4 + prr;
        int sp = ebase + wpos;
        const bool valid = (sp < E_);
        if (!valid) sp = E_ - 1;
        unsigned int st = sorted[(size_t)pass * E_ + sp];
        int s = (int)(st & 0xffffu), t = (int)(st >> 16);
        tgt_s[e] = valid ? t : -1;
        w_acc[e] = 0.0f;
        const float* zs = zb + (size_t)s * 13;
        const float* zt = zb + (size_t)t * 13;
        float fs[13], ft[13];
        __builtin_memcpy(fs, zs, 13 * sizeof(float));
        __builtin_memcpy(ft, zt, 13 * sizeof(float));
        float d0 = fs[0] - ft[0], d1 = fs[1] - ft[1], d2 = fs[2] - ft[2];
        float dist = d0 * d0 + d1 * d1 + d2 * d2;
        float c0 = fs[4] * ft[5] - fs[5] * ft[4];
        float c1 = fs[5] * ft[3] - fs[3] * ft[5];
        float c2 = fs[3] * ft[4] - fs[4] * ft[3];
        float vxn = sqrtf(c0 * c0 + c1 * c1 + c2 * c2);
        unsigned short row[40];
        #pragma unroll
        for (int j = 0; j < 13; j++) { row[j] = f2bf(fs[j]); row[13 + j] = f2bf(ft[j]); }
        row[26] = f2bf(d0); row[27] = f2bf(d1); row[28] = f2bf(d2); row[29] = f2bf(dist);
        row[30] = f2bf(c0); row[31] = f2bf(c1); row[32] = f2bf(c2); row[33] = f2bf(vxn);
        #pragma unroll
        for (int j = 34; j < 40; j++) row[j] = 0;
        #pragma unroll
        for (int v = 0; v < 5; v++) {
            short8 sv;
            #pragma unroll
            for (int j = 0; j < 8; j++) sv[j] = (short)row[v * 8 + j];
            *((short8*)&Abuf[e][v * 8]) = sv;
        }
    }
    __syncthreads();

    // ---- Layer 1: hidden = tanh(inp @ W1 + b1) for m-MLP and gate-MLP ----
    #pragma unroll 1
    for (int rt = 0; rt < 8; rt++) {
        const unsigned short* ar = &Abuf[rt * 16 + c][0];
        short8 a0 = *((const short8*)(ar + quad * 8));
        short8 a1 = {};
        if (quad == 0) a1 = *((const short8*)(ar + 32));   // cols 32..39 (34+ zero)
        float wpart[4] = {0.f, 0.f, 0.f, 0.f};
        #pragma unroll
        for (int i = 0; i < 2; i++) {
            f32x4 accm = {bias1m[i], bias1m[i], bias1m[i], bias1m[i]};
            f32x4 accw = {bias1w[i], bias1w[i], bias1w[i], bias1w[i]};
            accm = mfma16(a0, bm[i][0], accm);
            accm = mfma16(a1, bm[i][1], accm);
            accw = mfma16(a0, bw[i][0], accw);
            accw = mfma16(a1, bw[i][1], accw);
            int n = (nt0 + i) * 16 + c;
            #pragma unroll
            for (int r = 0; r < 4; r++) {
                Hbuf[rt * 16 + quad * 4 + r][n] = f2bf(tanh_fast(accm[r]));
                wpart[r] += tanh_fast(accw[r]) * w2v[i];
            }
        }
        #pragma unroll
        for (int r = 0; r < 4; r++) {
            float v = wpart[r];
            v += __shfl_xor(v, 1); v += __shfl_xor(v, 2);
            v += __shfl_xor(v, 4); v += __shfl_xor(v, 8);
            if (c == r) atomicAdd(&w_acc[rt * 16 + quad * 4 + r], v);
        }
    }
    __syncthreads();
    if (tid < 128) w_acc[tid] = sigmoid_fast(w_acc[tid] + wbias);
    __syncthreads();

    // ---- Layer 2: segmented window reduce, boundary-only atomics ----
    {
        const int n0 = nt0 * 16 + c;
        const int n1 = n0 + 16;
        int   tp = -1;
        float va0 = 0.f, va1 = 0.f;
        bool  from_start = true;     // current run includes window's first edge
        #pragma unroll 1
        for (int rt = 0; rt < 8; rt++) {
            const unsigned short* hr = &Hbuf[rt * 16 + c][0];
            short8 h0 = *((const short8*)(hr + quad * 8));
            short8 h1 = *((const short8*)(hr + 32 + quad * 8));
            short8 h2 = *((const short8*)(hr + 64 + quad * 8));
            short8 h3 = *((const short8*)(hr + 96 + quad * 8));
            f32x4 accA = {bias2m[0], bias2m[0], bias2m[0], bias2m[0]};
            f32x4 accB = {bias2m[1], bias2m[1], bias2m[1], bias2m[1]};
            accA = mfma16(h0, b2f[0][0], accA);
            accA = mfma16(h1, b2f[0][1], accA);
            accA = mfma16(h2, b2f[0][2], accA);
            accA = mfma16(h3, b2f[0][3], accA);
            accB = mfma16(h0, b2f[1][0], accB);
            accB = mfma16(h1, b2f[1][1], accB);
            accB = mfma16(h2, b2f[1][2], accB);
            accB = mfma16(h3, b2f[1][3], accB);
            const int elq = rt * 16 + quad * 4;
            #pragma unroll
            for (int r = 0; r < 4; r++) {
                const int row = elq + r;
                const int tg = tgt_s[row];
                const float g = w_acc[row];
                const float v0 = accA[r] * g;
                const float v1 = accB[r] * g;
                if (tg == tp) {
                    va0 += v0; va1 += v1;
                } else {
                    if (tp >= 0) {
                        float* dst = aggp + (size_t)tp * 128;
                        if (from_start) { atomicAdd(dst + n0, va0); atomicAdd(dst + n1, va1); }
                        else            { dst[n0] = va0; dst[n1] = va1; }
                    }
                    tp = tg; va0 = v0; va1 = v1;
                    from_start = (rt == 0 && r == 0);
                }
            }
        }
        if (tp >= 0) {   // final run touches window end -> must be atomic
            float* dst = aggp + (size_t)tp * 128;
            atomicAdd(dst + n0, va0);
            atomicAdd(dst + n1, va1);
        }
    }
}

// ---------------------------------------------------------------------------
// Fused node kernel — persistent grid-stride blocks + register-prefetch
// double-buffered pipeline (R6). R10: 6 blocks/CU (R5 precedent: node
// responds to occupancy), NODE_BLOCKS 1536. LDS 23.3 KB * 6 = 140 KB OK.
// K layout: [agg_h(128)|agg_w(128)|z(13)|pad -> 288].
// ---------------------------------------------------------------------------
#define NODE_BLOCKS 1536
__launch_bounds__(256, 6)
__global__ void node_fused(const float* __restrict__ z,
                           const float* __restrict__ agg,
                           const unsigned short* __restrict__ fb,
                           const float* __restrict__ nb1,
                           const float* __restrict__ nb2,
                           float* __restrict__ out) {
    __shared__ alignas(16) unsigned short Abuf[2][16][296];
    __shared__ alignas(16) unsigned short Hbuf[16][136];

    const int tid  = threadIdx.x;
    const int lane = tid & 63, wv = tid >> 6, quad = lane >> 4, c = lane & 15;
    const int nl = tid >> 4, part = tid & 15;
    constexpr int NT_TILES = (B_ * N_) / 16;   // 6250

    // zero pad cols 269..287 of BOTH buffers once (never rewritten per tile)
    for (int j = tid; j < 2 * 16 * 19; j += 256) {
        int bufi = j / (16 * 19), jj = j % (16 * 19);
        Abuf[bufi][jj / 19][269 + jj % 19] = 0;
    }

    const short8* F1 = (const short8*)(fb + OFF_NW1);
    const short8* F2 = (const short8*)(fb + OFF_NW2);
    const int nt0 = wv * 2;
    const float b1a = nb1[nt0 * 16 + c];
    const float b1b = nb1[(nt0 + 1) * 16 + c];
    const float bias2 = (c < 13) ? nb2[c] : 0.0f;

    f32x4 pa0, pa1, pb0, pb1;   // prefetch regs: s=0 (pa), s=1 (pb)
    float pz = 0.0f;

    int t = blockIdx.x;
    if (t >= NT_TILES) return;

    // ---- prologue prefetch ----
    {
        const int g = t * 16 + nl;
        const int b = (g >= N_) ? 1 : 0;
        const int tt = g - b * N_;
        const float* ap0 = agg + ((size_t)b * N_ + tt) * 128 + part * 8;
        const float* ap1 = agg + ((size_t)(2 + b) * N_ + tt) * 128 + part * 8;
        pa0 = *(const f32x4*)(ap0); pa1 = *(const f32x4*)(ap0 + 4);
        pb0 = *(const f32x4*)(ap1); pb1 = *(const f32x4*)(ap1 + 4);
        if (tid < 208) pz = z[(size_t)(t * 16 + tid / 13) * 13 + (tid % 13)];
    }

    int buf = 0;
    for (; t < NT_TILES; t += NODE_BLOCKS) {
        const int g0 = t * 16;
        // ---- drain prefetch into LDS ----
        {
            ushort8 u;
            #pragma unroll
            for (int k = 0; k < 4; k++) { u[k] = f2bf(pa0[k]); u[4 + k] = f2bf(pa1[k]); }
            *((ushort8*)&Abuf[buf][nl][part * 8]) = u;
            #pragma unroll
            for (int k = 0; k < 4; k++) { u[k] = f2bf(pb0[k]); u[4 + k] = f2bf(pb1[k]); }
            *((ushort8*)&Abuf[buf][nl][128 + part * 8]) = u;
            if (tid < 208) Abuf[buf][tid / 13][256 + tid % 13] = f2bf(pz);
        }
        // ---- issue next tile's loads (hide HBM latency under compute) ----
        const int tn = t + NODE_BLOCKS;
        if (tn < NT_TILES) {
            const int g = tn * 16 + nl;
            const int b = (g >= N_) ? 1 : 0;
            const int tt = g - b * N_;
            const float* ap0 = agg + ((size_t)b * N_ + tt) * 128 + part * 8;
            const float* ap1 = agg + ((size_t)(2 + b) * N_ + tt) * 128 + part * 8;
            pa0 = *(const f32x4*)(ap0); pa1 = *(const f32x4*)(ap0 + 4);
            pb0 = *(const f32x4*)(ap1); pb1 = *(const f32x4*)(ap1 + 4);
            if (tid < 208) pz = z[(size_t)(tn * 16 + tid / 13) * 13 + (tid % 13)];
        }
        __syncthreads();

        // ---- Layer 1: wave wv owns n-tiles wv*2, wv*2+1 ----
        {
            f32x4 acc0 = {b1a, b1a, b1a, b1a};
            f32x4 acc1 = {b1b, b1b, b1b, b1b};
            #pragma unroll
            for (int ks = 0; ks < 9; ks++) {
                short8 a = *((const short8*)(&Abuf[buf][c][0] + ks * 32 + quad * 8));
                acc0 = mfma16(a, F1[(ks * 8 + nt0) * 64 + lane], acc0);
                acc1 = mfma16(a, F1[(ks * 8 + nt0 + 1) * 64 + lane], acc1);
            }
            #pragma unroll
            for (int r = 0; r < 4; r++) {
                Hbuf[quad * 4 + r][nt0 * 16 + c]       = f2bf(tanh_fast(acc0[r]));
                Hbuf[quad * 4 + r][(nt0 + 1) * 16 + c] = f2bf(tanh_fast(acc1[r]));
            }
        }
        __syncthreads();

        // ---- Layer 2: wave 0 only (16x13 output) ----
        if (wv == 0) {
            f32x4 acc = {bias2, bias2, bias2, bias2};
            #pragma unroll
            for (int ks = 0; ks < 4; ks++) {
                short8 h = *((const short8*)(&Hbuf[c][0] + ks * 32 + quad * 8));
                acc = mfma16(h, F2[ks * 64 + lane], acc);
            }
            #pragma unroll
            for (int r = 0; r < 4; r++) {
                int g = g0 + quad * 4 + r;
                if (c < 13) out[(size_t)g * 13 + c] = acc[r];
            }
        }
        buf ^= 1;
        // no third barrier needed: next iteration's Abuf write targets buf^1
        // (last read two barriers ago) and its Hbuf write is fenced by the
        // next __syncthreads (wave 0 reaches it only after finishing L2).
    }
}

// ---------------------------------------------------------------------------
extern "C" void kernel_launch(void* const* d_in, const int* in_sizes, int n_in,
                              void* d_out, int out_size, void* d_ws, size_t ws_size,
                              hipStream_t stream) {
    const float* z   = (const float*)d_in[0];
    const int* ehh   = (const int*)d_in[1];
    const int* eww   = (const int*)d_in[2];
    const float* ew1 = (const float*)d_in[3];
    const float* eb1 = (const float*)d_in[4];
    const float* ew2 = (const float*)d_in[5];
    const float* eb2 = (const float*)d_in[6];
    const float* ww1 = (const float*)d_in[7];
    const float* wb1 = (const float*)d_in[8];
    const float* ww2 = (const float*)d_in[9];
    const float* wb2 = (const float*)d_in[10];
    const float* xw1 = (const float*)d_in[11];
    const float* xb1 = (const float*)d_in[12];
    const float* xw2 = (const float*)d_in[13];
    const float* xb2 = (const float*)d_in[14];
    const float* yw1 = (const float*)d_in[15];
    const float* yb1 = (const float*)d_in[16];
    const float* yw2 = (const float*)d_in[17];
    const float* yb2 = (const float*)d_in[18];
    const float* nw1 = (const float*)d_in[19];
    const float* nb1 = (const float*)d_in[20];
    const float* nw2 = (const float*)d_in[21];
    const float* nb2 = (const float*)d_in[22];

    float* agg  = (float*)d_ws;
    int* hist   = (int*)((char*)d_ws + AGG_BYTES);
    unsigned int* sorted = (unsigned int*)((char*)d_ws + AGG_BYTES + HIST_BYTES);
    unsigned short* frag = (unsigned short*)((char*)d_ws + AGG_BYTES + HIST_BYTES + SORT_BYTES);

    prep_kernel<<<dim3(72, 8), 256, 0, stream>>>(ew1, ww1, ew2, xw1, yw1, xw2, nw1, nw2,
                                                 frag, (uint4v*)hist, (uint4v*)agg);
    hist_kernel<<<dim3((E_ + 255) / 256, 4), 256, 0, stream>>>(ehh, eww, hist);
    scan_kernel<<<4, 1024, 0, stream>>>(hist);
    scatter_kernel<<<dim3((E_ + 255) / 256, 4), 256, 0, stream>>>(ehh, eww, hist, sorted);
    edge_kernel_agg<<<dim3((E_ + 127) / 128, 4), 256, 0, stream>>>(
        z, sorted, frag, agg,
        eb1, wb1, ww2, wb2, eb2,
        xb1, yb1, yw2, yb2, xb2);
    node_fused<<<NODE_BLOCKS, 256, 0, stream>>>(
        z, agg, frag, nb1, nb2, (float*)d_out);
}

// Round 11
// 398.025 us; speedup vs baseline: 1.2438x; 1.2438x over previous
//
#include <hip/hip_runtime.h>
#include <hip/hip_bf16.h>

// Problem constants
#define B_   2
#define N_   50000
#define FD_  13
#define E_   250000
#define M_   128
#define H_   128

typedef __attribute__((ext_vector_type(8))) short  short8;
typedef __attribute__((ext_vector_type(8))) __bf16 bf16x8;
typedef __attribute__((ext_vector_type(4))) float  f32x4;
typedef __attribute__((ext_vector_type(4))) unsigned int uint4v;
typedef __attribute__((ext_vector_type(8))) unsigned short ushort8;

// ws layout: [agg f32 4*N*128][hist][sorted(packed st)][frags]  (~107 MB)
#define AGG_BYTES  (4ull * N_ * 128 * 4)          // 102,400,000
#define HIST_BYTES (4ull * N_ * 4)                // 800,000
#define SORT_BYTES (4ull * E_ * 4)                // 4,000,000
// fragment offsets in ushort units (each frag = 64 lanes * 8 ush = 1KB)
#define OFF_EW1 0u
#define OFF_WW1 8192u
#define OFF_EW2 16384u
#define OFF_XW1 32768u
#define OFF_YW1 40960u
#define OFF_XW2 49152u
#define OFF_NW1 65536u    // 72 frags (K=288 reordered: [agg_h 0..127|agg_w 128..255|z 256..268|pad])
#define OFF_NW2 102400u

__device__ __forceinline__ float bf2f(unsigned short u) {
    unsigned int v = ((unsigned int)u) << 16;
    return __builtin_bit_cast(float, v);
}
// HW bf16 convert on gfx950.
__device__ __forceinline__ unsigned short f2bf(float f) {
    __bf16 h = (__bf16)f;
    return __builtin_bit_cast(unsigned short, h);
}
// exp2-folded transcendentals (A/B-verified in R9/R10: edge 191.5 -> 189 us).
__device__ __forceinline__ float tanh_fast(float x) {
    float e = __builtin_amdgcn_exp2f(x * 2.8853900817779268f);   // e^(2x)
    float r = __builtin_amdgcn_rcpf(e + 1.0f);
    return __builtin_fmaf(-2.0f, r, 1.0f);         // 1 - 2/(e+1)
}
__device__ __forceinline__ float sigmoid_fast(float x) {
    float e = __builtin_amdgcn_exp2f(x * -1.4426950408889634f);  // e^(-x)
    return __builtin_amdgcn_rcpf(1.0f + e);
}
__device__ __forceinline__ f32x4 mfma16(short8 a, short8 b, f32x4 c) {
    return __builtin_amdgcn_mfma_f32_16x16x32_bf16(
        __builtin_bit_cast(bf16x8, a), __builtin_bit_cast(bf16x8, b), c, 0, 0, 0);
}

// ---------------------------------------------------------------------------
// Prep: fp32 weights -> bf16 B-fragment-major.
// Fragment (ks,nt): lane l holds B[k = ks*32 + (l>>4)*8 + j][n = nt*16 + (l&15)]
// Also zeroes hist (runs before hist_kernel). 64 threads (R6 proven form —
// R10's 256-thread + agg-fill variant regressed; fill belongs in scatter
// where it overlaps atomic latency).
// ---------------------------------------------------------------------------
__global__ void prep_kernel(const float* __restrict__ ew1, const float* __restrict__ ww1,
                            const float* __restrict__ ew2, const float* __restrict__ xw1,
                            const float* __restrict__ yw1, const float* __restrict__ xw2,
                            const float* __restrict__ nw1, const float* __restrict__ nw2,
                            unsigned short* __restrict__ fb, uint4v* __restrict__ hist4) {
    int m = blockIdx.y, f = blockIdx.x, l = threadIdx.x;
    // hist zero: 800,000 B = 50,000 uint4
    {
        unsigned int flat = ((unsigned int)m * gridDim.x + (unsigned int)f) * 64u + (unsigned int)l;
        const uint4v zv = {0u, 0u, 0u, 0u};
        for (unsigned int i = flat; i < 50000u; i += gridDim.x * gridDim.y * 64u)
            hist4[i] = zv;
    }
    const float* src; int K, Nn, KS; unsigned int off;
    switch (m) {
        case 0: src = ew1; K = 34;  Nn = 128; KS = 2; off = OFF_EW1; break;
        case 1: src = ww1; K = 34;  Nn = 128; KS = 2; off = OFF_WW1; break;
        case 2: src = ew2; K = 128; Nn = 128; KS = 4; off = OFF_EW2; break;
        case 3: src = xw1; K = 34;  Nn = 128; KS = 2; off = OFF_XW1; break;
        case 4: src = yw1; K = 34;  Nn = 128; KS = 2; off = OFF_YW1; break;
        case 5: src = xw2; K = 128; Nn = 128; KS = 4; off = OFF_XW2; break;
        case 6: src = nw1; K = 269; Nn = 128; KS = 9; off = OFF_NW1; break;
        default: src = nw2; K = 128; Nn = 13; KS = 4; off = OFF_NW2; break;
    }
    int NT = (Nn + 15) / 16;
    if (f >= KS * NT) return;
    int ks = f / NT, nt = f % NT;
    int n = nt * 16 + (l & 15);
    unsigned short* dst = fb + off + ((unsigned int)f * 64u + (unsigned int)l) * 8u;
    #pragma unroll
    for (int j = 0; j < 8; j++) {
        int k = ks * 32 + ((l >> 4) * 8) + j;
        int kk = k; bool valid = (k < K) && (n < Nn);
        if (m == 6) {
            if (k < 256)      kk = k + 13;
            else if (k < 269) kk = k - 256;
            else              valid = false;
            valid = valid && (n < Nn);
        }
        dst[j] = valid ? f2bf(src[kk * Nn + n]) : (unsigned short)0;
    }
}

// ---------------------------------------------------------------------------
// Counting sort of edges by target, per pass p (p&1=batch, p>>1=set).
// ---------------------------------------------------------------------------
__global__ void hist_kernel(const int* __restrict__ ehh, const int* __restrict__ eww,
                            int* __restrict__ hist) {
    int p = blockIdx.y, idx = blockIdx.x * 256 + threadIdx.x;
    if (idx >= E_) return;
    const int* eg = ((p >> 1) ? eww : ehh) + (size_t)(p & 1) * 2 * E_;
    atomicAdd(&hist[p * N_ + eg[E_ + idx]], 1);
}

// chunk = 52 ints (208 B, 16B-aligned) per thread; values register-cached.
__global__ void scan_kernel(int* __restrict__ hist) {
    __shared__ int part[1024];
    const int p = blockIdx.x, tid = threadIdx.x;
    int* h = hist + p * N_;
    const int lo = tid * 52;
    int cnt = N_ - lo; if (cnt < 0) cnt = 0; if (cnt > 52) cnt = 52;
    int v[52];
    int sum = 0;
    if (cnt == 52) {
        const int4* src = (const int4*)(h + lo);
        #pragma unroll
        for (int i = 0; i < 13; i++) {
            int4 t = src[i];
            v[4*i] = t.x; v[4*i+1] = t.y; v[4*i+2] = t.z; v[4*i+3] = t.w;
        }
        #pragma unroll
        for (int i = 0; i < 52; i++) sum += v[i];
    } else {
        for (int i = 0; i < cnt; i++) sum += h[lo + i];
    }
    part[tid] = sum;
    __syncthreads();
    for (int off = 1; off < 1024; off <<= 1) {
        int t = (tid >= off) ? part[tid - off] : 0;
        __syncthreads();
        part[tid] += t;
        __syncthreads();
    }
    int excl = (tid == 0) ? 0 : part[tid - 1];
    if (cnt == 52) {
        int4* dst = (int4*)(h + lo);
        #pragma unroll
        for (int i = 0; i < 13; i++) {
            int4 o;
            o.x = excl; excl += v[4*i];
            o.y = excl; excl += v[4*i+1];
            o.z = excl; excl += v[4*i+2];
            o.w = excl; excl += v[4*i+3];
            dst[i] = o;
        }
    } else {
        for (int i = 0; i < cnt; i++) { int t = h[lo + i]; h[lo + i] = excl; excl += t; }
    }
}

// Writes PACKED endpoints (s | t<<16; N=50000 < 2^16) at the sorted position.
// Also zeroes agg (102.4 MB) via grid-stride dwordx4 stores — the fill
// overlaps the scatter's atomic-latency-bound execution (R6 proven form).
__global__ void scatter_kernel(const int* __restrict__ ehh, const int* __restrict__ eww,
                               int* __restrict__ hist, unsigned int* __restrict__ sorted,
                               uint4v* __restrict__ agg4) {
    int p = blockIdx.y, idx = blockIdx.x * 256 + threadIdx.x;
    // agg zero: 102,400,000 B = 6,400,000 uint4 over ~1.0M threads
    {
        unsigned int flat = ((unsigned int)p * gridDim.x + (unsigned int)blockIdx.x) * 256u
                          + (unsigned int)threadIdx.x;
        const unsigned int nthr = gridDim.x * gridDim.y * 256u;
        const uint4v zv = {0u, 0u, 0u, 0u};
        for (unsigned int i = flat; i < 6400000u; i += nthr) agg4[i] = zv;
    }
    if (idx >= E_) return;
    const int* eg = ((p >> 1) ? eww : ehh) + (size_t)(p & 1) * 2 * E_;
    int s = eg[idx];
    int t = eg[E_ + idx];
    int pos = atomicAdd(&hist[p * N_ + t], 1);   // after: hist[t] = end offset
    sorted[(size_t)p * E_ + pos] = (unsigned int)s | ((unsigned int)t << 16);
}

// ---------------------------------------------------------------------------
// Edge kernel — EXACT R6 structure (proven 189-192 us). 3 blocks/CU is FINAL:
// 4/CU (R7) and 5/CU (R4) blow the L2 dirty-line window (+55..+600 MB HBM);
// 8-wave blocks (R9) double the reduce cost; bf16 agg (R8) loses on
// sub-dword stores. Monolithic Hbuf, 256 threads, window-permuted rows +
// segmented reduce, boundary-only f32 atomics.
// ---------------------------------------------------------------------------
__launch_bounds__(256, 3)
__global__ void edge_kernel_agg(const float* __restrict__ z,
                                const unsigned int* __restrict__ sorted,
                                const unsigned short* __restrict__ fb,
                                float* __restrict__ agg,
                                const float* __restrict__ eb1, const float* __restrict__ wb1,
                                const float* __restrict__ ww2, const float* __restrict__ wb2,
                                const float* __restrict__ eb2,
                                const float* __restrict__ xb1, const float* __restrict__ yb1,
                                const float* __restrict__ yw2, const float* __restrict__ yb2,
                                const float* __restrict__ xb2) {
    __shared__ alignas(16) unsigned short Abuf[128][48];   // cols 0..39 used
    __shared__ alignas(16) unsigned short Hbuf[128][136];
    __shared__ float w_acc[128];   // gate partial sums, then sigmoid in place
    __shared__ int   tgt_s[128];   // target per ROW (-1 = invalid/pad)

    const int tid  = threadIdx.x;
    const int lane = tid & 63, wv = tid >> 6, quad = lane >> 4, c = lane & 15;
    const int pass = blockIdx.y, b = pass & 1, set = pass >> 1;
    const int ebase = blockIdx.x * 128;

    const float* zb = z + (size_t)b * N_ * FD_;
    float* aggp = agg + (size_t)pass * N_ * 128;

    const short8* Fm1 = (const short8*)(fb + (set ? OFF_XW1 : OFF_EW1));
    const short8* Fw1 = (const short8*)(fb + (set ? OFF_YW1 : OFF_WW1));
    const short8* Fm2 = (const short8*)(fb + (set ? OFF_XW2 : OFF_EW2));
    const float* B1m = set ? xb1 : eb1;
    const float* B1w = set ? yb1 : wb1;
    const float* B2m = set ? xb2 : eb2;
    const float* Wv2 = set ? yw2 : ww2;
    const float wbias = (set ? yb2 : wb2)[0];

    const int nt0 = wv * 2;
    short8 bm[2][2], bw[2][2], b2f[2][4];
    float bias1m[2], bias1w[2], bias2m[2], w2v[2];
    #pragma unroll
    for (int i = 0; i < 2; i++) {
        int nt = nt0 + i, n = nt * 16 + c;
        #pragma unroll
        for (int ks = 0; ks < 2; ks++) { bm[i][ks] = Fm1[(ks * 8 + nt) * 64 + lane];
                                         bw[i][ks] = Fw1[(ks * 8 + nt) * 64 + lane]; }
        #pragma unroll
        for (int ks = 0; ks < 4; ks++) { b2f[i][ks] = Fm2[(ks * 8 + nt) * 64 + lane]; }
        bias1m[i] = B1m[n]; bias1w[i] = B1w[n];
        bias2m[i] = B2m[n]; w2v[i] = Wv2[n];
    }

    // ---- Stage edge features (threads 0..127, one sorted edge each) ----
    // Row p holds sorted edge ebase + wpos(p), wpos = quad(p)*32 + rt(p)*4 + r(p)
    if (tid < 128) {
        const int e = tid;                                 // Abuf/Hbuf row
        const int prt = e >> 4, pqd = (e >> 2) & 3, prr = e & 3;
        const int wpos = pqd * 32 + prt * 4 + prr;
        int sp = ebase + wpos;
        const bool valid = (sp < E_);
        if (!valid) sp = E_ - 1;
        unsigned int st = sorted[(size_t)pass * E_ + sp];
        int s = (int)(st & 0xffffu), t = (int)(st >> 16);
        tgt_s[e] = valid ? t : -1;
        w_acc[e] = 0.0f;
        const float* zs = zb + (size_t)s * 13;
        const float* zt = zb + (size_t)t * 13;
        float fs[13], ft[13];
        __builtin_memcpy(fs, zs, 13 * sizeof(float));
        __builtin_memcpy(ft, zt, 13 * sizeof(float));
        float d0 = fs[0] - ft[0], d1 = fs[1] - ft[1], d2 = fs[2] - ft[2];
        float dist = d0 * d0 + d1 * d1 + d2 * d2;
        float c0 = fs[4] * ft[5] - fs[5] * ft[4];
        float c1 = fs[5] * ft[3] - fs[3] * ft[5];
        float c2 = fs[3] * ft[4] - fs[4] * ft[3];
        float vxn = sqrtf(c0 * c0 + c1 * c1 + c2 * c2);
        unsigned short row[40];
        #pragma unroll
        for (int j = 0; j < 13; j++) { row[j] = f2bf(fs[j]); row[13 + j] = f2bf(ft[j]); }
        row[26] = f2bf(d0); row[27] = f2bf(d1); row[28] = f2bf(d2); row[29] = f2bf(dist);
        row[30] = f2bf(c0); row[31] = f2bf(c1); row[32] = f2bf(c2); row[33] = f2bf(vxn);
        #pragma unroll
        for (int j = 34; j < 40; j++) row[j] = 0;
        #pragma unroll
        for (int v = 0; v < 5; v++) {
            short8 sv;
            #pragma unroll
            for (int j = 0; j < 8; j++) sv[j] = (short)row[v * 8 + j];
            *((short8*)&Abuf[e][v * 8]) = sv;
        }
    }
    __syncthreads();

    // ---- Layer 1: hidden = tanh(inp @ W1 + b1) for m-MLP and gate-MLP ----
    #pragma unroll 1
    for (int rt = 0; rt < 8; rt++) {
        const unsigned short* ar = &Abuf[rt * 16 + c][0];
        short8 a0 = *((const short8*)(ar + quad * 8));
        short8 a1 = {};
        if (quad == 0) a1 = *((const short8*)(ar + 32));   // cols 32..39 (34+ zero)
        float wpart[4] = {0.f, 0.f, 0.f, 0.f};
        #pragma unroll
        for (int i = 0; i < 2; i++) {
            f32x4 accm = {bias1m[i], bias1m[i], bias1m[i], bias1m[i]};
            f32x4 accw = {bias1w[i], bias1w[i], bias1w[i], bias1w[i]};
            accm = mfma16(a0, bm[i][0], accm);
            accm = mfma16(a1, bm[i][1], accm);
            accw = mfma16(a0, bw[i][0], accw);
            accw = mfma16(a1, bw[i][1], accw);
            int n = (nt0 + i) * 16 + c;
            #pragma unroll
            for (int r = 0; r < 4; r++) {
                Hbuf[rt * 16 + quad * 4 + r][n] = f2bf(tanh_fast(accm[r]));
                wpart[r] += tanh_fast(accw[r]) * w2v[i];
            }
        }
        #pragma unroll
        for (int r = 0; r < 4; r++) {
            float v = wpart[r];
            v += __shfl_xor(v, 1); v += __shfl_xor(v, 2);
            v += __shfl_xor(v, 4); v += __shfl_xor(v, 8);
            if (c == r) atomicAdd(&w_acc[rt * 16 + quad * 4 + r], v);
        }
    }
    __syncthreads();
    if (tid < 128) w_acc[tid] = sigmoid_fast(w_acc[tid] + wbias);
    __syncthreads();

    // ---- Layer 2: segmented window reduce, boundary-only atomics ----
    {
        const int n0 = nt0 * 16 + c;
        const int n1 = n0 + 16;
        int   tp = -1;
        float va0 = 0.f, va1 = 0.f;
        bool  from_start = true;     // current run includes window's first edge
        #pragma unroll 1
        for (int rt = 0; rt < 8; rt++) {
            const unsigned short* hr = &Hbuf[rt * 16 + c][0];
            short8 h0 = *((const short8*)(hr + quad * 8));
            short8 h1 = *((const short8*)(hr + 32 + quad * 8));
            short8 h2 = *((const short8*)(hr + 64 + quad * 8));
            short8 h3 = *((const short8*)(hr + 96 + quad * 8));
            f32x4 accA = {bias2m[0], bias2m[0], bias2m[0], bias2m[0]};
            f32x4 accB = {bias2m[1], bias2m[1], bias2m[1], bias2m[1]};
            accA = mfma16(h0, b2f[0][0], accA);
            accA = mfma16(h1, b2f[0][1], accA);
            accA = mfma16(h2, b2f[0][2], accA);
            accA = mfma16(h3, b2f[0][3], accA);
            accB = mfma16(h0, b2f[1][0], accB);
            accB = mfma16(h1, b2f[1][1], accB);
            accB = mfma16(h2, b2f[1][2], accB);
            accB = mfma16(h3, b2f[1][3], accB);
            const int elq = rt * 16 + quad * 4;
            #pragma unroll
            for (int r = 0; r < 4; r++) {
                const int row = elq + r;
                const int tg = tgt_s[row];
                const float g = w_acc[row];
                const float v0 = accA[r] * g;
                const float v1 = accB[r] * g;
                if (tg == tp) {
                    va0 += v0; va1 += v1;
                } else {
                    if (tp >= 0) {
                        float* dst = aggp + (size_t)tp * 128;
                        if (from_start) { atomicAdd(dst + n0, va0); atomicAdd(dst + n1, va1); }
                        else            { dst[n0] = va0; dst[n1] = va1; }
                    }
                    tp = tg; va0 = v0; va1 = v1;
                    from_start = (rt == 0 && r == 0);
                }
            }
        }
        if (tp >= 0) {   // final run touches window end -> must be atomic
            float* dst = aggp + (size_t)tp * 128;
            atomicAdd(dst + n0, va0);
            atomicAdd(dst + n1, va1);
        }
    }
}

// ---------------------------------------------------------------------------
// Fused node kernel — persistent grid-stride blocks + register-prefetch
// double-buffered pipeline (EXACT R6: launch_bounds(256,4), 1024 blocks).
// R10 lesson: (256,6) forces VGPR<=64 -> the prefetch registers spill ->
// catastrophic. 4 blocks/CU is the register-budget optimum for this kernel.
// K layout: [agg_h(128)|agg_w(128)|z(13)|pad -> 288].
// ---------------------------------------------------------------------------
#define NODE_BLOCKS 1024
__launch_bounds__(256, 4)
__global__ void node_fused(const float* __restrict__ z,
                           const float* __restrict__ agg,
                           const unsigned short* __restrict__ fb,
                           const float* __restrict__ nb1,
                           const float* __restrict__ nb2,
                           float* __restrict__ out) {
    __shared__ alignas(16) unsigned short Abuf[2][16][296];
    __shared__ alignas(16) unsigned short Hbuf[16][136];

    const int tid  = threadIdx.x;
    const int lane = tid & 63, wv = tid >> 6, quad = lane >> 4, c = lane & 15;
    const int nl = tid >> 4, part = tid & 15;
    constexpr int NT_TILES = (B_ * N_) / 16;   // 6250

    // zero pad cols 269..287 of BOTH buffers once (never rewritten per tile)
    for (int j = tid; j < 2 * 16 * 19; j += 256) {
        int bufi = j / (16 * 19), jj = j % (16 * 19);
        Abuf[bufi][jj / 19][269 + jj % 19] = 0;
    }

    const short8* F1 = (const short8*)(fb + OFF_NW1);
    const short8* F2 = (const short8*)(fb + OFF_NW2);
    const int nt0 = wv * 2;
    const float b1a = nb1[nt0 * 16 + c];
    const float b1b = nb1[(nt0 + 1) * 16 + c];
    const float bias2 = (c < 13) ? nb2[c] : 0.0f;

    f32x4 pa0, pa1, pb0, pb1;   // prefetch regs: s=0 (pa), s=1 (pb)
    float pz = 0.0f;

    int t = blockIdx.x;

    // ---- prologue prefetch ----
    {
        const int g = t * 16 + nl;
        const int b = (g >= N_) ? 1 : 0;
        const int tt = g - b * N_;
        const float* ap0 = agg + ((size_t)b * N_ + tt) * 128 + part * 8;
        const float* ap1 = agg + ((size_t)(2 + b) * N_ + tt) * 128 + part * 8;
        pa0 = *(const f32x4*)(ap0); pa1 = *(const f32x4*)(ap0 + 4);
        pb0 = *(const f32x4*)(ap1); pb1 = *(const f32x4*)(ap1 + 4);
        if (tid < 208) pz = z[(size_t)(t * 16 + tid / 13) * 13 + (tid % 13)];
    }

    int buf = 0;
    for (; t < NT_TILES; t += NODE_BLOCKS) {
        const int g0 = t * 16;
        // ---- drain prefetch into LDS ----
        {
            ushort8 u;
            #pragma unroll
            for (int k = 0; k < 4; k++) { u[k] = f2bf(pa0[k]); u[4 + k] = f2bf(pa1[k]); }
            *((ushort8*)&Abuf[buf][nl][part * 8]) = u;
            #pragma unroll
            for (int k = 0; k < 4; k++) { u[k] = f2bf(pb0[k]); u[4 + k] = f2bf(pb1[k]); }
            *((ushort8*)&Abuf[buf][nl][128 + part * 8]) = u;
            if (tid < 208) Abuf[buf][tid / 13][256 + tid % 13] = f2bf(pz);
        }
        // ---- issue next tile's loads (hide HBM latency under compute) ----
        const int tn = t + NODE_BLOCKS;
        if (tn < NT_TILES) {
            const int g = tn * 16 + nl;
            const int b = (g >= N_) ? 1 : 0;
            const int tt = g - b * N_;
            const float* ap0 = agg + ((size_t)b * N_ + tt) * 128 + part * 8;
            const float* ap1 = agg + ((size_t)(2 + b) * N_ + tt) * 128 + part * 8;
            pa0 = *(const f32x4*)(ap0); pa1 = *(const f32x4*)(ap0 + 4);
            pb0 = *(const f32x4*)(ap1); pb1 = *(const f32x4*)(ap1 + 4);
            if (tid < 208) pz = z[(size_t)(tn * 16 + tid / 13) * 13 + (tid % 13)];
        }
        __syncthreads();

        // ---- Layer 1: wave wv owns n-tiles wv*2, wv*2+1 ----
        {
            f32x4 acc0 = {b1a, b1a, b1a, b1a};
            f32x4 acc1 = {b1b, b1b, b1b, b1b};
            #pragma unroll
            for (int ks = 0; ks < 9; ks++) {
                short8 a = *((const short8*)(&Abuf[buf][c][0] + ks * 32 + quad * 8));
                acc0 = mfma16(a, F1[(ks * 8 + nt0) * 64 + lane], acc0);
                acc1 = mfma16(a, F1[(ks * 8 + nt0 + 1) * 64 + lane], acc1);
            }
            #pragma unroll
            for (int r = 0; r < 4; r++) {
                Hbuf[quad * 4 + r][nt0 * 16 + c]       = f2bf(tanh_fast(acc0[r]));
                Hbuf[quad * 4 + r][(nt0 + 1) * 16 + c] = f2bf(tanh_fast(acc1[r]));
            }
        }
        __syncthreads();

        // ---- Layer 2: wave 0 only (16x13 output) ----
        if (wv == 0) {
            f32x4 acc = {bias2, bias2, bias2, bias2};
            #pragma unroll
            for (int ks = 0; ks < 4; ks++) {
                short8 h = *((const short8*)(&Hbuf[c][0] + ks * 32 + quad * 8));
                acc = mfma16(h, F2[ks * 64 + lane], acc);
            }
            #pragma unroll
            for (int r = 0; r < 4; r++) {
                int g = g0 + quad * 4 + r;
                if (c < 13) out[(size_t)g * 13 + c] = acc[r];
            }
        }
        buf ^= 1;
        // no third barrier needed: next iteration's Abuf write targets buf^1
        // (last read two barriers ago) and its Hbuf write is fenced by the
        // next __syncthreads (wave 0 reaches it only after finishing L2).
    }
}

// ---------------------------------------------------------------------------
extern "C" void kernel_launch(void* const* d_in, const int* in_sizes, int n_in,
                              void* d_out, int out_size, void* d_ws, size_t ws_size,
                              hipStream_t stream) {
    const float* z   = (const float*)d_in[0];
    const int* ehh   = (const int*)d_in[1];
    const int* eww   = (const int*)d_in[2];
    const float* ew1 = (const float*)d_in[3];
    const float* eb1 = (const float*)d_in[4];
    const float* ew2 = (const float*)d_in[5];
    const float* eb2 = (const float*)d_in[6];
    const float* ww1 = (const float*)d_in[7];
    const float* wb1 = (const float*)d_in[8];
    const float* ww2 = (const float*)d_in[9];
    const float* wb2 = (const float*)d_in[10];
    const float* xw1 = (const float*)d_in[11];
    const float* xb1 = (const float*)d_in[12];
    const float* xw2 = (const float*)d_in[13];
    const float* xb2 = (const float*)d_in[14];
    const float* yw1 = (const float*)d_in[15];
    const float* yb1 = (const float*)d_in[16];
    const float* yw2 = (const float*)d_in[17];
    const float* yb2 = (const float*)d_in[18];
    const float* nw1 = (const float*)d_in[19];
    const float* nb1 = (const float*)d_in[20];
    const float* nw2 = (const float*)d_in[21];
    const float* nb2 = (const float*)d_in[22];

    float* agg  = (float*)d_ws;
    int* hist   = (int*)((char*)d_ws + AGG_BYTES);
    unsigned int* sorted = (unsigned int*)((char*)d_ws + AGG_BYTES + HIST_BYTES);
    unsigned short* frag = (unsigned short*)((char*)d_ws + AGG_BYTES + HIST_BYTES + SORT_BYTES);

    prep_kernel<<<dim3(72, 8), 64, 0, stream>>>(ew1, ww1, ew2, xw1, yw1, xw2, nw1, nw2,
                                                frag, (uint4v*)hist);
    hist_kernel<<<dim3((E_ + 255) / 256, 4), 256, 0, stream>>>(ehh, eww, hist);
    scan_kernel<<<4, 1024, 0, stream>>>(hist);
    scatter_kernel<<<dim3((E_ + 255) / 256, 4), 256, 0, stream>>>(ehh, eww, hist, sorted,
                                                                  (uint4v*)agg);
    edge_kernel_agg<<<dim3((E_ + 127) / 128, 4), 256, 0, stream>>>(
        z, sorted, frag, agg,
        eb1, wb1, ww2, wb2, eb2,
        xb1, yb1, yw2, yb2, xb2);
    node_fused<<<NODE_BLOCKS, 256, 0, stream>>>(
        z, agg, frag, nb1, nb2, (float*)d_out);
}

// Round 13
// 393.309 us; speedup vs baseline: 1.2587x; 1.0120x over previous
//
#include <hip/hip_runtime.h>
#include <hip/hip_bf16.h>

// Problem constants
#define B_   2
#define N_   50000
#define FD_  13
#define E_   250000
#define M_   128
#define H_   128

typedef __attribute__((ext_vector_type(8))) short  short8;
typedef __attribute__((ext_vector_type(8))) __bf16 bf16x8;
typedef __attribute__((ext_vector_type(4))) float  f32x4;
typedef __attribute__((ext_vector_type(4))) unsigned int uint4v;
typedef __attribute__((ext_vector_type(8))) unsigned short ushort8;

// ws layout: [agg f32 4*N*128][hist][sorted(packed st)][frags]  (~107 MB)
#define AGG_BYTES  (4ull * N_ * 128 * 4)          // 102,400,000
#define HIST_BYTES (4ull * N_ * 4)                // 800,000
#define SORT_BYTES (4ull * E_ * 4)                // 4,000,000
// fragment offsets in ushort units (each frag = 64 lanes * 8 ush = 1KB)
#define OFF_EW1 0u
#define OFF_WW1 8192u
#define OFF_EW2 16384u
#define OFF_XW1 32768u
#define OFF_YW1 40960u
#define OFF_XW2 49152u
#define OFF_NW1 65536u    // 72 frags (K=288 reordered: [agg_h 0..127|agg_w 128..255|z 256..268|pad])
#define OFF_NW2 102400u

__device__ __forceinline__ float bf2f(unsigned short u) {
    unsigned int v = ((unsigned int)u) << 16;
    return __builtin_bit_cast(float, v);
}
// HW bf16 convert on gfx950.
__device__ __forceinline__ unsigned short f2bf(float f) {
    __bf16 h = (__bf16)f;
    return __builtin_bit_cast(unsigned short, h);
}
// exp2-folded transcendentals (A/B-verified in R9/R10: edge 191.5 -> 189 us).
__device__ __forceinline__ float tanh_fast(float x) {
    float e = __builtin_amdgcn_exp2f(x * 2.8853900817779268f);   // e^(2x)
    float r = __builtin_amdgcn_rcpf(e + 1.0f);
    return __builtin_fmaf(-2.0f, r, 1.0f);         // 1 - 2/(e+1)
}
__device__ __forceinline__ float sigmoid_fast(float x) {
    float e = __builtin_amdgcn_exp2f(x * -1.4426950408889634f);  // e^(-x)
    return __builtin_amdgcn_rcpf(1.0f + e);
}
__device__ __forceinline__ f32x4 mfma16(short8 a, short8 b, f32x4 c) {
    return __builtin_amdgcn_mfma_f32_16x16x32_bf16(
        __builtin_bit_cast(bf16x8, a), __builtin_bit_cast(bf16x8, b), c, 0, 0, 0);
}

// ---------------------------------------------------------------------------
// Prep: fp32 weights -> bf16 B-fragment-major.
// Fragment (ks,nt): lane l holds B[k = ks*32 + (l>>4)*8 + j][n = nt*16 + (l&15)]
// Also zeroes hist (runs before hist_kernel). 64 threads (R6 proven form).
// ---------------------------------------------------------------------------
__global__ void prep_kernel(const float* __restrict__ ew1, const float* __restrict__ ww1,
                            const float* __restrict__ ew2, const float* __restrict__ xw1,
                            const float* __restrict__ yw1, const float* __restrict__ xw2,
                            const float* __restrict__ nw1, const float* __restrict__ nw2,
                            unsigned short* __restrict__ fb, uint4v* __restrict__ hist4) {
    int m = blockIdx.y, f = blockIdx.x, l = threadIdx.x;
    // hist zero: 800,000 B = 50,000 uint4
    {
        unsigned int flat = ((unsigned int)m * gridDim.x + (unsigned int)f) * 64u + (unsigned int)l;
        const uint4v zv = {0u, 0u, 0u, 0u};
        for (unsigned int i = flat; i < 50000u; i += gridDim.x * gridDim.y * 64u)
            hist4[i] = zv;
    }
    const float* src; int K, Nn, KS; unsigned int off;
    switch (m) {
        case 0: src = ew1; K = 34;  Nn = 128; KS = 2; off = OFF_EW1; break;
        case 1: src = ww1; K = 34;  Nn = 128; KS = 2; off = OFF_WW1; break;
        case 2: src = ew2; K = 128; Nn = 128; KS = 4; off = OFF_EW2; break;
        case 3: src = xw1; K = 34;  Nn = 128; KS = 2; off = OFF_XW1; break;
        case 4: src = yw1; K = 34;  Nn = 128; KS = 2; off = OFF_YW1; break;
        case 5: src = xw2; K = 128; Nn = 128; KS = 4; off = OFF_XW2; break;
        case 6: src = nw1; K = 269; Nn = 128; KS = 9; off = OFF_NW1; break;
        default: src = nw2; K = 128; Nn = 13; KS = 4; off = OFF_NW2; break;
    }
    int NT = (Nn + 15) / 16;
    if (f >= KS * NT) return;
    int ks = f / NT, nt = f % NT;
    int n = nt * 16 + (l & 15);
    unsigned short* dst = fb + off + ((unsigned int)f * 64u + (unsigned int)l) * 8u;
    #pragma unroll
    for (int j = 0; j < 8; j++) {
        int k = ks * 32 + ((l >> 4) * 8) + j;
        int kk = k; bool valid = (k < K) && (n < Nn);
        if (m == 6) {
            if (k < 256)      kk = k + 13;
            else if (k < 269) kk = k - 256;
            else              valid = false;
            valid = valid && (n < Nn);
        }
        dst[j] = valid ? f2bf(src[kk * Nn + n]) : (unsigned short)0;
    }
}

// ---------------------------------------------------------------------------
// Counting sort of edges by target, per pass p (p&1=batch, p>>1=set).
// ---------------------------------------------------------------------------
__global__ void hist_kernel(const int* __restrict__ ehh, const int* __restrict__ eww,
                            int* __restrict__ hist) {
    int p = blockIdx.y, idx = blockIdx.x * 256 + threadIdx.x;
    if (idx >= E_) return;
    const int* eg = ((p >> 1) ? eww : ehh) + (size_t)(p & 1) * 2 * E_;
    atomicAdd(&hist[p * N_ + eg[E_ + idx]], 1);
}

// chunk = 52 ints (208 B, 16B-aligned) per thread; values register-cached.
__global__ void scan_kernel(int* __restrict__ hist) {
    __shared__ int part[1024];
    const int p = blockIdx.x, tid = threadIdx.x;
    int* h = hist + p * N_;
    const int lo = tid * 52;
    int cnt = N_ - lo; if (cnt < 0) cnt = 0; if (cnt > 52) cnt = 52;
    int v[52];
    int sum = 0;
    if (cnt == 52) {
        const int4* src = (const int4*)(h + lo);
        #pragma unroll
        for (int i = 0; i < 13; i++) {
            int4 t = src[i];
            v[4*i] = t.x; v[4*i+1] = t.y; v[4*i+2] = t.z; v[4*i+3] = t.w;
        }
        #pragma unroll
        for (int i = 0; i < 52; i++) sum += v[i];
    } else {
        for (int i = 0; i < cnt; i++) sum += h[lo + i];
    }
    part[tid] = sum;
    __syncthreads();
    for (int off = 1; off < 1024; off <<= 1) {
        int t = (tid >= off) ? part[tid - off] : 0;
        __syncthreads();
        part[tid] += t;
        __syncthreads();
    }
    int excl = (tid == 0) ? 0 : part[tid - 1];
    if (cnt == 52) {
        int4* dst = (int4*)(h + lo);
        #pragma unroll
        for (int i = 0; i < 13; i++) {
            int4 o;
            o.x = excl; excl += v[4*i];
            o.y = excl; excl += v[4*i+1];
            o.z = excl; excl += v[4*i+2];
            o.w = excl; excl += v[4*i+3];
            dst[i] = o;
        }
    } else {
        for (int i = 0; i < cnt; i++) { int t = h[lo + i]; h[lo + i] = excl; excl += t; }
    }
}

// Writes PACKED endpoints (s | t<<16; N=50000 < 2^16) at the sorted position.
// Also zeroes agg (102.4 MB) via grid-stride dwordx4 stores — the fill
// overlaps the scatter's atomic-latency-bound execution (R6 proven form).
__global__ void scatter_kernel(const int* __restrict__ ehh, const int* __restrict__ eww,
                               int* __restrict__ hist, unsigned int* __restrict__ sorted,
                               uint4v* __restrict__ agg4) {
    int p = blockIdx.y, idx = blockIdx.x * 256 + threadIdx.x;
    // agg zero: 102,400,000 B = 6,400,000 uint4 over ~1.0M threads
    {
        unsigned int flat = ((unsigned int)p * gridDim.x + (unsigned int)blockIdx.x) * 256u
                          + (unsigned int)threadIdx.x;
        const unsigned int nthr = gridDim.x * gridDim.y * 256u;
        const uint4v zv = {0u, 0u, 0u, 0u};
        for (unsigned int i = flat; i < 6400000u; i += nthr) agg4[i] = zv;
    }
    if (idx >= E_) return;
    const int* eg = ((p >> 1) ? eww : ehh) + (size_t)(p & 1) * 2 * E_;
    int s = eg[idx];
    int t = eg[E_ + idx];
    int pos = atomicAdd(&hist[p * N_ + t], 1);   // after: hist[t] = end offset
    sorted[(size_t)p * E_ + pos] = (unsigned int)s | ((unsigned int)t << 16);
}

// ---------------------------------------------------------------------------
// Edge kernel — R11 structure; R12: ILP via unroll. VGPR was 68 vs a ~170
// budget at 3 waves/SIMD — the 48% VALU-idle gap is dependent-chain latency
// (tanh = mul->exp2->add->rcp->fma, ~40 cy) with only 3 waves to hide it.
// Unroll 4 (L1) / 2 (L2) lets the compiler interleave independent chains.
// 3 blocks/CU is FINAL (R4/R7: L2 dirty-line window; R9: 8-wave reduce cost;
// R8: bf16 agg sub-dword stores).
// ---------------------------------------------------------------------------
__launch_bounds__(256, 3)
__global__ void edge_kernel_agg(const float* __restrict__ z,
                                const unsigned int* __restrict__ sorted,
                                const unsigned short* __restrict__ fb,
                                float* __restrict__ agg,
                                const float* __restrict__ eb1, const float* __restrict__ wb1,
                                const float* __restrict__ ww2, const float* __restrict__ wb2,
                                const float* __restrict__ eb2,
                                const float* __restrict__ xb1, const float* __restrict__ yb1,
                                const float* __restrict__ yw2, const float* __restrict__ yb2,
                                const float* __restrict__ xb2) {
    __shared__ alignas(16) unsigned short Abuf[128][48];   // cols 0..39 used
    __shared__ alignas(16) unsigned short Hbuf[128][136];
    __shared__ float w_acc[128];   // gate partial sums, then sigmoid in place
    __shared__ int   tgt_s[128];   // target per ROW (-1 = invalid/pad)

    const int tid  = threadIdx.x;
    const int lane = tid & 63, wv = tid >> 6, quad = lane >> 4, c = lane & 15;
    const int pass = blockIdx.y, b = pass & 1, set = pass >> 1;
    const int ebase = blockIdx.x * 128;

    const float* zb = z + (size_t)b * N_ * FD_;
    float* aggp = agg + (size_t)pass * N_ * 128;

    const short8* Fm1 = (const short8*)(fb + (set ? OFF_XW1 : OFF_EW1));
    const short8* Fw1 = (const short8*)(fb + (set ? OFF_YW1 : OFF_WW1));
    const short8* Fm2 = (const short8*)(fb + (set ? OFF_XW2 : OFF_EW2));
    const float* B1m = set ? xb1 : eb1;
    const float* B1w = set ? yb1 : wb1;
    const float* B2m = set ? xb2 : eb2;
    const float* Wv2 = set ? yw2 : ww2;
    const float wbias = (set ? yb2 : wb2)[0];

    const int nt0 = wv * 2;
    short8 bm[2][2], bw[2][2], b2f[2][4];
    float bias1m[2], bias1w[2], bias2m[2], w2v[2];
    #pragma unroll
    for (int i = 0; i < 2; i++) {
        int nt = nt0 + i, n = nt * 16 + c;
        #pragma unroll
        for (int ks = 0; ks < 2; ks++) { bm[i][ks] = Fm1[(ks * 8 + nt) * 64 + lane];
                                         bw[i][ks] = Fw1[(ks * 8 + nt) * 64 + lane]; }
        #pragma unroll
        for (int ks = 0; ks < 4; ks++) { b2f[i][ks] = Fm2[(ks * 8 + nt) * 64 + lane]; }
        bias1m[i] = B1m[n]; bias1w[i] = B1w[n];
        bias2m[i] = B2m[n]; w2v[i] = Wv2[n];
    }

    // ---- Stage edge features (threads 0..127, one sorted edge each) ----
    // Row p holds sorted edge ebase + wpos(p), wpos = quad(p)*32 + rt(p)*4 + r(p)
    if (tid < 128) {
        const int e = tid;                                 // Abuf/Hbuf row
        const int prt = e >> 4, pqd = (e >> 2) & 3, prr = e & 3;
        const int wpos = pqd * 32 + prt * 4 + prr;
        int sp = ebase + wpos;
        const bool valid = (sp < E_);
        if (!valid) sp = E_ - 1;
        unsigned int st = sorted[(size_t)pass * E_ + sp];
        int s = (int)(st & 0xffffu), t = (int)(st >> 16);
        tgt_s[e] = valid ? t : -1;
        w_acc[e] = 0.0f;
        const float* zs = zb + (size_t)s * 13;
        const float* zt = zb + (size_t)t * 13;
        float fs[13], ft[13];
        __builtin_memcpy(fs, zs, 13 * sizeof(float));
        __builtin_memcpy(ft, zt, 13 * sizeof(float));
        float d0 = fs[0] - ft[0], d1 = fs[1] - ft[1], d2 = fs[2] - ft[2];
        float dist = d0 * d0 + d1 * d1 + d2 * d2;
        float c0 = fs[4] * ft[5] - fs[5] * ft[4];
        float c1 = fs[5] * ft[3] - fs[3] * ft[5];
        float c2 = fs[3] * ft[4] - fs[4] * ft[3];
        float vxn = sqrtf(c0 * c0 + c1 * c1 + c2 * c2);
        unsigned short row[40];
        #pragma unroll
        for (int j = 0; j < 13; j++) { row[j] = f2bf(fs[j]); row[13 + j] = f2bf(ft[j]); }
        row[26] = f2bf(d0); row[27] = f2bf(d1); row[28] = f2bf(d2); row[29] = f2bf(dist);
        row[30] = f2bf(c0); row[31] = f2bf(c1); row[32] = f2bf(c2); row[33] = f2bf(vxn);
        #pragma unroll
        for (int j = 34; j < 40; j++) row[j] = 0;
        #pragma unroll
        for (int v = 0; v < 5; v++) {
            short8 sv;
            #pragma unroll
            for (int j = 0; j < 8; j++) sv[j] = (short)row[v * 8 + j];
            *((short8*)&Abuf[e][v * 8]) = sv;
        }
    }
    __syncthreads();

    // ---- Layer 1: hidden = tanh(inp @ W1 + b1) for m-MLP and gate-MLP ----
    // R12: unroll 4 — interleaves 4 independent tanh/MFMA chains per wave.
    #pragma unroll 4
    for (int rt = 0; rt < 8; rt++) {
        const unsigned short* ar = &Abuf[rt * 16 + c][0];
        short8 a0 = *((const short8*)(ar + quad * 8));
        short8 a1 = {};
        if (quad == 0) a1 = *((const short8*)(ar + 32));   // cols 32..39 (34+ zero)
        float wpart[4] = {0.f, 0.f, 0.f, 0.f};
        #pragma unroll
        for (int i = 0; i < 2; i++) {
            f32x4 accm = {bias1m[i], bias1m[i], bias1m[i], bias1m[i]};
            f32x4 accw = {bias1w[i], bias1w[i], bias1w[i], bias1w[i]};
            accm = mfma16(a0, bm[i][0], accm);
            accm = mfma16(a1, bm[i][1], accm);
            accw = mfma16(a0, bw[i][0], accw);
            accw = mfma16(a1, bw[i][1], accw);
            int n = (nt0 + i) * 16 + c;
            #pragma unroll
            for (int r = 0; r < 4; r++) {
                Hbuf[rt * 16 + quad * 4 + r][n] = f2bf(tanh_fast(accm[r]));
                wpart[r] += tanh_fast(accw[r]) * w2v[i];
            }
        }
        #pragma unroll
        for (int r = 0; r < 4; r++) {
            float v = wpart[r];
            v += __shfl_xor(v, 1); v += __shfl_xor(v, 2);
            v += __shfl_xor(v, 4); v += __shfl_xor(v, 8);
            if (c == r) atomicAdd(&w_acc[rt * 16 + quad * 4 + r], v);
        }
    }
    __syncthreads();
    if (tid < 128) w_acc[tid] = sigmoid_fast(w_acc[tid] + wbias);
    __syncthreads();

    // ---- Layer 2: segmented window reduce, boundary-only atomics ----
    // R12: unroll 2 — MFMA/ds_read of iteration rt+1 overlaps rt's reduce.
    {
        const int n0 = nt0 * 16 + c;
        const int n1 = n0 + 16;
        int   tp = -1;
        float va0 = 0.f, va1 = 0.f;
        bool  from_start = true;     // current run includes window's first edge
        #pragma unroll 2
        for (int rt = 0; rt < 8; rt++) {
            const unsigned short* hr = &Hbuf[rt * 16 + c][0];
            short8 h0 = *((const short8*)(hr + quad * 8));
            short8 h1 = *((const short8*)(hr + 32 + quad * 8));
            short8 h2 = *((const short8*)(hr + 64 + quad * 8));
            short8 h3 = *((const short8*)(hr + 96 + quad * 8));
            f32x4 accA = {bias2m[0], bias2m[0], bias2m[0], bias2m[0]};
            f32x4 accB = {bias2m[1], bias2m[1], bias2m[1], bias2m[1]};
            accA = mfma16(h0, b2f[0][0], accA);
            accA = mfma16(h1, b2f[0][1], accA);
            accA = mfma16(h2, b2f[0][2], accA);
            accA = mfma16(h3, b2f[0][3], accA);
            accB = mfma16(h0, b2f[1][0], accB);
            accB = mfma16(h1, b2f[1][1], accB);
            accB = mfma16(h2, b2f[1][2], accB);
            accB = mfma16(h3, b2f[1][3], accB);
            const int elq = rt * 16 + quad * 4;
            #pragma unroll
            for (int r = 0; r < 4; r++) {
                const int row = elq + r;
                const int tg = tgt_s[row];
                const float g = w_acc[row];
                const float v0 = accA[r] * g;
                const float v1 = accB[r] * g;
                if (tg == tp) {
                    va0 += v0; va1 += v1;
                } else {
                    if (tp >= 0) {
                        float* dst = aggp + (size_t)tp * 128;
                        if (from_start) { atomicAdd(dst + n0, va0); atomicAdd(dst + n1, va1); }
                        else            { dst[n0] = va0; dst[n1] = va1; }
                    }
                    tp = tg; va0 = v0; va1 = v1;
                    from_start = (rt == 0 && r == 0);
                }
            }
        }
        if (tp >= 0) {   // final run touches window end -> must be atomic
            float* dst = aggp + (size_t)tp * 128;
            atomicAdd(dst + n0, va0);
            atomicAdd(dst + n1, va1);
        }
    }
}

// ---------------------------------------------------------------------------
// Fused node kernel — persistent grid-stride blocks + register-prefetch
// double-buffered pipeline (EXACT R6: launch_bounds(256,4), 1024 blocks).
// R10 lesson: (256,6) forces VGPR<=64 -> prefetch registers spill. 4/CU is
// the register-budget optimum. K layout: [agg_h(128)|agg_w(128)|z(13)|pad].
// ---------------------------------------------------------------------------
#define NODE_BLOCKS 1024
__launch_bounds__(256, 4)
__global__ void node_fused(const float* __restrict__ z,
                           const float* __restrict__ agg,
                           const unsigned short* __restrict__ fb,
                           const float* __restrict__ nb1,
                           const float* __restrict__ nb2,
                           float* __restrict__ out) {
    __shared__ alignas(16) unsigned short Abuf[2][16][296];
    __shared__ alignas(16) unsigned short Hbuf[16][136];

    const int tid  = threadIdx.x;
    const int lane = tid & 63, wv = tid >> 6, quad = lane >> 4, c = lane & 15;
    const int nl = tid >> 4, part = tid & 15;
    constexpr int NT_TILES = (B_ * N_) / 16;   // 6250

    // zero pad cols 269..287 of BOTH buffers once (never rewritten per tile)
    for (int j = tid; j < 2 * 16 * 19; j += 256) {
        int bufi = j / (16 * 19), jj = j % (16 * 19);
        Abuf[bufi][jj / 19][269 + jj % 19] = 0;
    }

    const short8* F1 = (const short8*)(fb + OFF_NW1);
    const short8* F2 = (const short8*)(fb + OFF_NW2);
    const int nt0 = wv * 2;
    const float b1a = nb1[nt0 * 16 + c];
    const float b1b = nb1[(nt0 + 1) * 16 + c];
    const float bias2 = (c < 13) ? nb2[c] : 0.0f;

    f32x4 pa0, pa1, pb0, pb1;   // prefetch regs: s=0 (pa), s=1 (pb)
    float pz = 0.0f;

    int t = blockIdx.x;

    // ---- prologue prefetch ----
    {
        const int g = t * 16 + nl;
        const int b = (g >= N_) ? 1 : 0;
        const int tt = g - b * N_;
        const float* ap0 = agg + ((size_t)b * N_ + tt) * 128 + part * 8;
        const float* ap1 = agg + ((size_t)(2 + b) * N_ + tt) * 128 + part * 8;
        pa0 = *(const f32x4*)(ap0); pa1 = *(const f32x4*)(ap0 + 4);
        pb0 = *(const f32x4*)(ap1); pb1 = *(const f32x4*)(ap1 + 4);
        if (tid < 208) pz = z[(size_t)(t * 16 + tid / 13) * 13 + (tid % 13)];
    }

    int buf = 0;
    for (; t < NT_TILES; t += NODE_BLOCKS) {
        const int g0 = t * 16;
        // ---- drain prefetch into LDS ----
        {
            ushort8 u;
            #pragma unroll
            for (int k = 0; k < 4; k++) { u[k] = f2bf(pa0[k]); u[4 + k] = f2bf(pa1[k]); }
            *((ushort8*)&Abuf[buf][nl][part * 8]) = u;
            #pragma unroll
            for (int k = 0; k < 4; k++) { u[k] = f2bf(pb0[k]); u[4 + k] = f2bf(pb1[k]); }
            *((ushort8*)&Abuf[buf][nl][128 + part * 8]) = u;
            if (tid < 208) Abuf[buf][tid / 13][256 + tid % 13] = f2bf(pz);
        }
        // ---- issue next tile's loads (hide HBM latency under compute) ----
        const int tn = t + NODE_BLOCKS;
        if (tn < NT_TILES) {
            const int g = tn * 16 + nl;
            const int b = (g >= N_) ? 1 : 0;
            const int tt = g - b * N_;
            const float* ap0 = agg + ((size_t)b * N_ + tt) * 128 + part * 8;
            const float* ap1 = agg + ((size_t)(2 + b) * N_ + tt) * 128 + part * 8;
            pa0 = *(const f32x4*)(ap0); pa1 = *(const f32x4*)(ap0 + 4);
            pb0 = *(const f32x4*)(ap1); pb1 = *(const f32x4*)(ap1 + 4);
            if (tid < 208) pz = z[(size_t)(tn * 16 + tid / 13) * 13 + (tid % 13)];
        }
        __syncthreads();

        // ---- Layer 1: wave wv owns n-tiles wv*2, wv*2+1 ----
        {
            f32x4 acc0 = {b1a, b1a, b1a, b1a};
            f32x4 acc1 = {b1b, b1b, b1b, b1b};
            #pragma unroll
            for (int ks = 0; ks < 9; ks++) {
                short8 a = *((const short8*)(&Abuf[buf][c][0] + ks * 32 + quad * 8));
                acc0 = mfma16(a, F1[(ks * 8 + nt0) * 64 + lane], acc0);
                acc1 = mfma16(a, F1[(ks * 8 + nt0 + 1) * 64 + lane], acc1);
            }
            #pragma unroll
            for (int r = 0; r < 4; r++) {
                Hbuf[quad * 4 + r][nt0 * 16 + c]       = f2bf(tanh_fast(acc0[r]));
                Hbuf[quad * 4 + r][(nt0 + 1) * 16 + c] = f2bf(tanh_fast(acc1[r]));
            }
        }
        __syncthreads();

        // ---- Layer 2: wave 0 only (16x13 output) ----
        if (wv == 0) {
            f32x4 acc = {bias2, bias2, bias2, bias2};
            #pragma unroll
            for (int ks = 0; ks < 4; ks++) {
                short8 h = *((const short8*)(&Hbuf[c][0] + ks * 32 + quad * 8));
                acc = mfma16(h, F2[ks * 64 + lane], acc);
            }
            #pragma unroll
            for (int r = 0; r < 4; r++) {
                int g = g0 + quad * 4 + r;
                if (c < 13) out[(size_t)g * 13 + c] = acc[r];
            }
        }
        buf ^= 1;
        // no third barrier needed: next iteration's Abuf write targets buf^1
        // (last read two barriers ago) and its Hbuf write is fenced by the
        // next __syncthreads (wave 0 reaches it only after finishing L2).
    }
}

// ---------------------------------------------------------------------------
extern "C" void kernel_launch(void* const* d_in, const int* in_sizes, int n_in,
                              void* d_out, int out_size, void* d_ws, size_t ws_size,
                              hipStream_t stream) {
    const float* z   = (const float*)d_in[0];
    const int* ehh   = (const int*)d_in[1];
    const int* eww   = (const int*)d_in[2];
    const float* ew1 = (const float*)d_in[3];
    const float* eb1 = (const float*)d_in[4];
    const float* ew2 = (const float*)d_in[5];
    const float* eb2 = (const float*)d_in[6];
    const float* ww1 = (const float*)d_in[7];
    const float* wb1 = (const float*)d_in[8];
    const float* ww2 = (const float*)d_in[9];
    const float* wb2 = (const float*)d_in[10];
    const float* xw1 = (const float*)d_in[11];
    const float* xb1 = (const float*)d_in[12];
    const float* xw2 = (const float*)d_in[13];
    const float* xb2 = (const float*)d_in[14];
    const float* yw1 = (const float*)d_in[15];
    const float* yb1 = (const float*)d_in[16];
    const float* yw2 = (const float*)d_in[17];
    const float* yb2 = (const float*)d_in[18];
    const float* nw1 = (const float*)d_in[19];
    const float* nb1 = (const float*)d_in[20];
    const float* nw2 = (const float*)d_in[21];
    const float* nb2 = (const float*)d_in[22];

    float* agg  = (float*)d_ws;
    int* hist   = (int*)((char*)d_ws + AGG_BYTES);
    unsigned int* sorted = (unsigned int*)((char*)d_ws + AGG_BYTES + HIST_BYTES);
    unsigned short* frag = (unsigned short*)((char*)d_ws + AGG_BYTES + HIST_BYTES + SORT_BYTES);

    prep_kernel<<<dim3(72, 8), 64, 0, stream>>>(ew1, ww1, ew2, xw1, yw1, xw2, nw1, nw2,
                                                frag, (uint4v*)hist);
    hist_kernel<<<dim3((E_ + 255) / 256, 4), 256, 0, stream>>>(ehh, eww, hist);
    scan_kernel<<<4, 1024, 0, stream>>>(hist);
    scatter_kernel<<<dim3((E_ + 255) / 256, 4), 256, 0, stream>>>(ehh, eww, hist, sorted,
                                                                  (uint4v*)agg);
    edge_kernel_agg<<<dim3((E_ + 127) / 128, 4), 256, 0, stream>>>(
        z, sorted, frag, agg,
        eb1, wb1, ww2, wb2, eb2,
        xb1, yb1, yw2, yb2, xb2);
    node_fused<<<NODE_BLOCKS, 256, 0, stream>>>(
        z, agg, frag, nb1, nb2, (float*)d_out);
}